// Round 8
// baseline (117.840 us; speedup 1.0000x reference)
//
#include <hip/hip_runtime.h>
#include <hip/hip_bf16.h>
#include <stdint.h>

// Batched NT-GEMM: out[b,i,j] = sum_d m1[b,i,d] * m2[b,j,d]
// B=16, M=N=2048, K=256, fp32 in/out; f16 MFMA compute.
//
// Round 8 = round 7 + ONE change: plain stores instead of nontemporal.
//   Theory: nt (no-allocate) stores ack at ~HBM latency; the end-of-block
//   vmcnt(0) drain of 64 stores/thread then serializes with compute in
//   per-CU lockstep (both co-resident blocks drain together) -> write bus
//   duty cycle ~50% (3.5 TB/s observed vs 7.0 fill ceiling). Plain stores
//   ack at L2; writeback overlaps the next block's compute.

typedef _Float16 f16x8 __attribute__((ext_vector_type(8)));
typedef _Float16 f16x4 __attribute__((ext_vector_type(4)));
typedef _Float16 f16x2 __attribute__((ext_vector_type(2)));
typedef float f32x4 __attribute__((ext_vector_type(4)));

#define NB 16
#define DM 2048
#define DN 2048
#define DK 256
#define BM 128
#define BN 128
#define BK 32
#define BKP 36                          // padded LDS row stride (elements)
#define NT (DK / BK)                    // 8 K-steps
#define NWG (NB * (DM/BM) * (DN/BN))    // 4096 blocks

// lgkm-only barrier: LDS writes published, VMEM loads stay outstanding.
#define LDS_BARRIER() do {                                   \
    asm volatile("s_waitcnt lgkmcnt(0)" ::: "memory");       \
    __builtin_amdgcn_s_barrier();                            \
    asm volatile("" ::: "memory");                           \
} while (0)

__global__ __launch_bounds__(256, 2) void fused_gemm(const float* __restrict__ A,
                                                     const float* __restrict__ B,
                                                     float* __restrict__ C) {
    __shared__ _Float16 As[2][BM * BKP];   // 9216 B per buffer
    __shared__ _Float16 Bs[2][BN * BKP];

    const int t = threadIdx.x;

    // XCD swizzle (NWG % 8 == 0 -> bijective). XCD k gets a contiguous chunk;
    // within a chunk bx is fastest (per-batch panels ~4MB ~ one XCD L2).
    const int bid = blockIdx.x;
    const int swz = (bid & 7) * (NWG / 8) + (bid >> 3);
    const int b    = swz >> 8;          // 256 blocks per batch
    const int rem  = swz & 255;
    const int brow = (rem >> 4) << 7;   // * BM
    const int bcol = (rem & 15) << 7;   // * BN

    const float* At = A + (size_t)b * DM * DK + (size_t)brow * DK;
    const float* Bt = B + (size_t)b * DN * DK + (size_t)bcol * DK;

    const int w    = t >> 6;
    const int l    = t & 63;
    const int wr   = (w >> 1) * 64;     // wave row offset in tile
    const int wc   = (w & 1) * 64;      // wave col offset in tile
    const int lrow = l & 15;
    const int lko  = (l >> 4) * 8;      // k-offset of lane's 8 f16 elements

    f32x4 acc[4][4] = {};

    // Staging geometry: tile = 128 rows x 32 k fp32 = 1024 float4 chunks;
    // thread t owns chunks c = t + i*256 -> row r = c>>3, quad q = c&7.
    auto issue = [&](int kt, float4 (&va)[4], float4 (&vb)[4]) {
#pragma unroll
        for (int i = 0; i < 4; ++i) {
            const int c = t + i * 256;
            const int r = c >> 3, q = c & 7;
            va[i] = *reinterpret_cast<const float4*>(At + (size_t)r * DK + kt * BK + q * 4);
            vb[i] = *reinterpret_cast<const float4*>(Bt + (size_t)r * DK + kt * BK + q * 4);
        }
    };
    auto wlds = [&](int buf, const float4 (&va)[4], const float4 (&vb)[4]) {
#pragma unroll
        for (int i = 0; i < 4; ++i) {
            const int c = t + i * 256;
            const int r = c >> 3, q = c & 7;
            f16x2 alo = __builtin_bit_cast(f16x2, __builtin_amdgcn_cvt_pkrtz(va[i].x, va[i].y));
            f16x2 ahi = __builtin_bit_cast(f16x2, __builtin_amdgcn_cvt_pkrtz(va[i].z, va[i].w));
            f16x2 blo = __builtin_bit_cast(f16x2, __builtin_amdgcn_cvt_pkrtz(vb[i].x, vb[i].y));
            f16x2 bhi = __builtin_bit_cast(f16x2, __builtin_amdgcn_cvt_pkrtz(vb[i].z, vb[i].w));
            f16x4 ha = { alo[0], alo[1], ahi[0], ahi[1] };
            f16x4 hb = { blo[0], blo[1], bhi[0], bhi[1] };
            *reinterpret_cast<f16x4*>(&As[buf][r * BKP + q * 4]) = ha;
            *reinterpret_cast<f16x4*>(&Bs[buf][r * BKP + q * 4]) = hb;
        }
    };
    auto compute = [&](int buf) {
        f16x8 af[4], bfr[4];
#pragma unroll
        for (int m = 0; m < 4; ++m)
            af[m] = *reinterpret_cast<const f16x8*>(&As[buf][(wr + m * 16 + lrow) * BKP + lko]);
#pragma unroll
        for (int n = 0; n < 4; ++n)
            bfr[n] = *reinterpret_cast<const f16x8*>(&Bs[buf][(wc + n * 16 + lrow) * BKP + lko]);
#pragma unroll
        for (int m = 0; m < 4; ++m)
#pragma unroll
            for (int n = 0; n < 4; ++n)
                acc[m][n] = __builtin_amdgcn_mfma_f32_16x16x32_f16(af[m], bfr[n], acc[m][n], 0, 0, 0);
    };

    // Two named in-flight register sets (static indexing only - rule #20).
    float4 vaX[4], vbX[4], vaY[4], vbY[4];

    // Prologue: tiles 0 (X) and 1 (Y) in flight; write tile 0 -> buf0.
    issue(0, vaX, vbX);
    issue(1, vaY, vbY);
    wlds(0, vaX, vbX);        // vmcnt(16): Y's loads stay outstanding
    LDS_BARRIER();

    // Steady state, manually unrolled x2 (roles X/Y alternate; buf = kt&1).
#pragma unroll
    for (int k2 = 0; k2 < NT; k2 += 2) {
        if (k2 + 2 < NT) issue(k2 + 2, vaX, vbX);
        compute(0);
        wlds(1, vaY, vbY);                 // vmcnt(16): X stays in flight
        LDS_BARRIER();

        if (k2 + 3 < NT) issue(k2 + 3, vaY, vbY);
        compute(1);
        if (k2 + 2 < NT) {
            wlds(0, vaX, vbX);             // vmcnt(16): Y stays in flight
        }
        LDS_BARRIER();
    }

    // Epilogue. C/D layout (m89/m91): col = lane&15, row = (lane>>4)*4 + reg.
    // Plain stores: ack at L2, async writeback overlaps next block's compute.
    float* Cb = C + (size_t)b * DM * DN;
    const int crow = brow + wr + (l >> 4) * 4;
    const int ccol = bcol + wc + lrow;
#pragma unroll
    for (int m = 0; m < 4; ++m)
#pragma unroll
        for (int j = 0; j < 4; ++j) {
            float* rowp = Cb + (size_t)(crow + m * 16 + j) * DN + ccol;
#pragma unroll
            for (int n = 0; n < 4; ++n)
                rowp[n * 16] = acc[m][n][j];
        }
}

extern "C" void kernel_launch(void* const* d_in, const int* in_sizes, int n_in,
                              void* d_out, int out_size, void* d_ws, size_t ws_size,
                              hipStream_t stream) {
    const float* m1 = (const float*)d_in[0];
    const float* m2 = (const float*)d_in[1];
    float* out = (float*)d_out;
    (void)d_ws; (void)ws_size;

    fused_gemm<<<NWG, 256, 0, stream>>>(m1, m2, out);
}

// Round 9
// 90.877 us; speedup vs baseline: 1.2967x; 1.2967x over previous
//
#include <hip/hip_runtime.h>
#include <hip/hip_bf16.h>
#include <stdint.h>

// Batched NT-GEMM: out[b,i,j] = sum_d m1[b,i,d] * m2[b,j,d]
// B=16, M=N=2048, K=256, fp32 in/out; f16 MFMA compute.
//
// Round 9 = R7 base (75.8us, nt stores) + M-SPLIT STORE STREAMING:
//  - Each block runs two phases: rows 0-63 then rows 64-127 (full K sweep each).
//  - Separate named acc0/acc1 (asm-pinned -> regalloc can't alias them onto
//    outstanding-store sources; avoids R6's WAR drain).
//  - Phase-0's 32 nt stores issue AFTER phase-1's first prefetch loads
//    (in-order vmcnt: early wlds waits gate on loads only) and drain under
//    phase-1's whole compute -> write bus streams instead of bursting at
//    block end. End-of-block drain halves (32 stores).
//  - A-tile halves (64x32): staging -16 VGPR, cvt -25%, LDS -9KB.

typedef _Float16 f16x8 __attribute__((ext_vector_type(8)));
typedef _Float16 f16x4 __attribute__((ext_vector_type(4)));
typedef _Float16 f16x2 __attribute__((ext_vector_type(2)));
typedef float f32x4 __attribute__((ext_vector_type(4)));

#define NB 16
#define DM 2048
#define DN 2048
#define DK 256
#define BM 128
#define BN 128
#define BK 32
#define BKP 36                          // padded LDS row stride (elements)
#define NT (DK / BK)                    // 8 K-steps per phase
#define NWG (NB * (DM/BM) * (DN/BN))    // 4096 blocks

// lgkm-only barrier: LDS writes published, VMEM ops stay outstanding.
#define LDS_BARRIER() do {                                   \
    asm volatile("s_waitcnt lgkmcnt(0)" ::: "memory");       \
    __builtin_amdgcn_s_barrier();                            \
    asm volatile("" ::: "memory");                           \
} while (0)

__global__ __launch_bounds__(256, 2) void fused_gemm(const float* __restrict__ A,
                                                     const float* __restrict__ B,
                                                     float* __restrict__ C) {
    __shared__ _Float16 As[2][64 * BKP];    // 4608 B per buffer (half A-tile)
    __shared__ _Float16 Bs[2][BN * BKP];    // 9216 B per buffer

    const int t = threadIdx.x;

    // XCD swizzle (NWG % 8 == 0 -> bijective).
    const int bid = blockIdx.x;
    const int swz = (bid & 7) * (NWG / 8) + (bid >> 3);
    const int b    = swz >> 8;          // 256 blocks per batch
    const int rem  = swz & 255;
    const int brow = (rem >> 4) << 7;   // * BM
    const int bcol = (rem & 15) << 7;   // * BN

    const float* At = A + (size_t)b * DM * DK + (size_t)brow * DK;
    const float* Bt = B + (size_t)b * DN * DK + (size_t)bcol * DK;

    const int w    = t >> 6;
    const int l    = t & 63;
    const int wrp  = (w >> 1) * 32;     // wave row offset within the 64-row phase
    const int wc   = (w & 1) * 64;      // wave col offset
    const int lrow = l & 15;
    const int lko  = (l >> 4) * 8;      // k-offset of lane's 8 f16 elements

    f32x4 acc0[2][4] = {};
    f32x4 acc1[2][4] = {};
    // Pin acc1 so its zero-init can't sink past phase-0 stores (which would let
    // regalloc alias acc1 onto acc0's regs -> WAR wait on outstanding stores).
    asm volatile("" :: "v"(acc1[0][0]), "v"(acc1[0][1]), "v"(acc1[0][2]), "v"(acc1[0][3]),
                       "v"(acc1[1][0]), "v"(acc1[1][1]), "v"(acc1[1][2]), "v"(acc1[1][3]));

    // Staging: A half = 64x32 fp32 = 512 f4 chunks (2/thread); B = 1024 (4/thread).
    auto issueA = [&](int p, int kt, float4 (&ax)[2]) {
#pragma unroll
        for (int i = 0; i < 2; ++i) {
            const int c = t + i * 256;
            const int r = c >> 3, q = c & 7;
            ax[i] = *reinterpret_cast<const float4*>(At + (size_t)(p * 64 + r) * DK + kt * BK + q * 4);
        }
    };
    auto issueB = [&](int kt, float4 (&bx)[4]) {
#pragma unroll
        for (int i = 0; i < 4; ++i) {
            const int c = t + i * 256;
            const int r = c >> 3, q = c & 7;
            bx[i] = *reinterpret_cast<const float4*>(Bt + (size_t)r * DK + kt * BK + q * 4);
        }
    };
    auto cvt4 = [](const float4& v) -> f16x4 {
        f16x2 lo = __builtin_bit_cast(f16x2, __builtin_amdgcn_cvt_pkrtz(v.x, v.y));
        f16x2 hi = __builtin_bit_cast(f16x2, __builtin_amdgcn_cvt_pkrtz(v.z, v.w));
        return f16x4{ lo[0], lo[1], hi[0], hi[1] };
    };
    auto wldsA = [&](int buf, const float4 (&ax)[2]) {
#pragma unroll
        for (int i = 0; i < 2; ++i) {
            const int c = t + i * 256;
            const int r = c >> 3, q = c & 7;
            *reinterpret_cast<f16x4*>(&As[buf][r * BKP + q * 4]) = cvt4(ax[i]);
        }
    };
    auto wldsB = [&](int buf, const float4 (&bx)[4]) {
#pragma unroll
        for (int i = 0; i < 4; ++i) {
            const int c = t + i * 256;
            const int r = c >> 3, q = c & 7;
            *reinterpret_cast<f16x4*>(&Bs[buf][r * BKP + q * 4]) = cvt4(bx[i]);
        }
    };
    auto compute = [&](int buf, f32x4 (&acc)[2][4]) {
        f16x8 af[2], bf[4];
#pragma unroll
        for (int m = 0; m < 2; ++m)
            af[m] = *reinterpret_cast<const f16x8*>(&As[buf][(wrp + m * 16 + lrow) * BKP + lko]);
#pragma unroll
        for (int n = 0; n < 4; ++n)
            bf[n] = *reinterpret_cast<const f16x8*>(&Bs[buf][(wc + n * 16 + lrow) * BKP + lko]);
#pragma unroll
        for (int m = 0; m < 2; ++m)
#pragma unroll
            for (int n = 0; n < 4; ++n)
                acc[m][n] = __builtin_amdgcn_mfma_f32_16x16x32_f16(af[m], bf[n], acc[m][n], 0, 0, 0);
    };

    float* Cb = C + (size_t)b * DM * DN;
    // C/D layout (m89/m91): col = lane&15, row = (lane>>4)*4 + reg.
    auto store_phase = [&](int p, const f32x4 (&acc)[2][4]) {
        const int crow = brow + p * 64 + wrp + (l >> 4) * 4;
        const int ccol = bcol + wc + lrow;
#pragma unroll
        for (int m = 0; m < 2; ++m)
#pragma unroll
            for (int j = 0; j < 4; ++j) {
                float* rowp = Cb + (size_t)(crow + m * 16 + j) * DN + ccol;
#pragma unroll
                for (int n = 0; n < 4; ++n)
                    __builtin_nontemporal_store(acc[m][n][j], rowp + n * 16);
            }
    };

    // Two named in-flight register sets (static indexing only - rule #20).
    float4 axX[2], bxX[4], axY[2], bxY[4];

    // ---------------- phase 0 (rows 0-63) ----------------
    issueA(0, 0, axX); issueB(0, bxX);
    issueA(0, 1, axY); issueB(1, bxY);
    wldsA(0, axX); wldsB(0, bxX);
    LDS_BARRIER();
#pragma unroll
    for (int k2 = 0; k2 < NT; k2 += 2) {
        if (k2 + 2 < NT) { issueA(0, k2 + 2, axX); issueB(k2 + 2, bxX); }
        compute(0, acc0);
        wldsA(1, axY); wldsB(1, bxY);
        LDS_BARRIER();
        if (k2 + 3 < NT) { issueA(0, k2 + 3, axY); issueB(k2 + 3, bxY); }
        compute(1, acc0);
        if (k2 + 2 < NT) { wldsA(0, axX); wldsB(0, bxX); }
        LDS_BARRIER();
    }

    // ---------------- phase transition ----------------
    // Phase-1 prefetch loads FIRST (oldest in vmcnt order), THEN phase-0
    // stores: the upcoming wlds waits gate on the loads only; the 32 stores
    // stay outstanding and drain under phase-1 compute.
    issueA(1, 0, axX); issueB(0, bxX);
    issueA(1, 1, axY); issueB(1, bxY);
    asm volatile("" ::: "memory");      // keep stores ordered after the loads
    store_phase(0, acc0);
    wldsA(0, axX); wldsB(0, bxX);
    LDS_BARRIER();

    // ---------------- phase 1 (rows 64-127) ----------------
#pragma unroll
    for (int k2 = 0; k2 < NT; k2 += 2) {
        if (k2 + 2 < NT) { issueA(1, k2 + 2, axX); issueB(k2 + 2, bxX); }
        compute(0, acc1);
        wldsA(1, axY); wldsB(1, bxY);
        LDS_BARRIER();
        if (k2 + 3 < NT) { issueA(1, k2 + 3, axY); issueB(k2 + 3, bxY); }
        compute(1, acc1);
        if (k2 + 2 < NT) { wldsA(0, axX); wldsB(0, bxX); }
        LDS_BARRIER();
    }

    store_phase(1, acc1);
}

extern "C" void kernel_launch(void* const* d_in, const int* in_sizes, int n_in,
                              void* d_out, int out_size, void* d_ws, size_t ws_size,
                              hipStream_t stream) {
    const float* m1 = (const float*)d_in[0];
    const float* m2 = (const float*)d_in[1];
    float* out = (float*)d_out;
    (void)d_ws; (void)ws_size;

    fused_gemm<<<NWG, 256, 0, stream>>>(m1, m2, out);
}